// Round 2
// baseline (287.778 us; speedup 1.0000x reference)
//
#include <hip/hip_runtime.h>

namespace {
constexpr int N_   = 1024;
constexpr int BND_ = 4;
constexpr int WP_  = N_ + 2 * BND_;   // 1032
constexpr int NN_  = N_ * N_;         // 1<<20

// Exact replication of reference gather: clip flat index into padded (WP x WP)
// sdf, then return pad value 1.0 or interior grid value.
__device__ __forceinline__ float fetch_pad(const float* __restrict__ gb, int idx) {
    idx = min(max(idx, 0), WP_ * WP_ - 1);
    int yy = idx / WP_;
    int xx = idx - yy * WP_;
    if (xx >= BND_ && xx < WP_ - BND_ && yy >= BND_ && yy < WP_ - BND_)
        return gb[(yy - BND_) * N_ + (xx - BND_)];
    return 1.0f;
}
} // namespace

__global__ __launch_bounds__(256) void advect_kernel(
    const float* __restrict__ grid,   // (B,N,N) fp32
    const float* __restrict__ vec,    // (B,N,N,2) fp32
    float* __restrict__ out,          // (B,N,N) fp32
    int total_quads)
{
    int t = blockIdx.x * blockDim.x + threadIdx.x;
    if (t >= total_quads) return;
    int g0  = t << 2;                 // first pixel of the quad (4 pixels, same row)
    int b   = g0 >> 20;               // / (N*N)
    int rem = g0 & (NN_ - 1);
    int j   = rem >> 10;
    int i0  = rem & (N_ - 1);

    // 4 pixels' displacement vectors: 8 floats = 32 bytes, coalesced & aligned
    const float4* vp = reinterpret_cast<const float4*>(vec + (size_t)g0 * 2);
    float4 v01 = vp[0];               // vx0, vy0, vx1, vy1
    float4 v23 = vp[1];               // vx2, vy2, vx3, vy3
    float vx[4] = {v01.x, v01.z, v23.x, v23.z};
    float vy[4] = {v01.y, v01.w, v23.y, v23.w};

    const float* gb = grid + (size_t)b * NN_;

    float res[4];
#pragma unroll
    for (int k = 0; k < 4; ++k) {
        // fp32 op order must match numpy: ((i+0.5) - vx) + 3.5
        float px = ((float)(i0 + k) + 0.5f - vx[k]) + 3.5f;
        float py = ((float)j        + 0.5f - vy[k]) + 3.5f;
        int x = (int)px;              // trunc toward zero, same as astype(int32)
        int y = (int)py;
        float fx = px - (float)x;
        float fy = py - (float)y;

        float g00, g01, g10, g11;
        if (x >= BND_ && x <= WP_ - BND_ - 2 && y >= BND_ && y <= WP_ - BND_ - 2) {
            // fast path: all 4 taps strictly inside the unpadded grid, no clip
            const float* p = gb + (y - BND_) * N_ + (x - BND_);
            g00 = p[0];
            g01 = p[1];
            g10 = p[N_];
            g11 = p[N_ + 1];
        } else {
            int idx = x + y * WP_;
            g00 = fetch_pad(gb, idx);
            g01 = fetch_pad(gb, idx + 1);
            g10 = fetch_pad(gb, idx + WP_);
            g11 = fetch_pad(gb, idx + WP_ + 1);
        }
        res[k] = g00 * (1.0f - fx) * (1.0f - fy)
               + g01 * fx          * (1.0f - fy)
               + g10 * (1.0f - fx) * fy
               + g11 * fx          * fy;
    }

    float4 o = make_float4(res[0], res[1], res[2], res[3]);
    *reinterpret_cast<float4*>(out + g0) = o;
}

extern "C" void kernel_launch(void* const* d_in, const int* in_sizes, int n_in,
                              void* d_out, int out_size, void* d_ws, size_t ws_size,
                              hipStream_t stream)
{
    const float* grid = (const float*)d_in[0];
    const float* vec  = (const float*)d_in[1];
    float* out = (float*)d_out;

    int total = in_sizes[0];          // B*N*N (16,777,216)
    int quads = total >> 2;
    int threads = 256;
    int blocks = (quads + threads - 1) / threads;
    advect_kernel<<<blocks, threads, 0, stream>>>(grid, vec, out, quads);
}

// Round 3
// 279.849 us; speedup vs baseline: 1.0283x; 1.0283x over previous
//
#include <hip/hip_runtime.h>

namespace {
constexpr int N_   = 1024;
constexpr int BND_ = 4;
constexpr int WP_  = N_ + 2 * BND_;   // 1032
constexpr int NN_  = N_ * N_;         // 1<<20

// Tile geometry: each 256-thread block computes a 128x32 pixel tile.
constexpr int TW_ = 128;
constexpr int TH_ = 32;
// Staged LDS window (pad-extended grid values), halo covers |v| <= ~8.
constexpr int CW_ = 152;              // cols: gi0 = it-12 .. it+139
constexpr int CH_ = 52;               // rows: gj0 = jt-9  .. jt+42
constexpr int TILES_X = N_ / TW_;     // 8
constexpr int TILES_Y = N_ / TH_;     // 32
constexpr int TILES_PER_IMG = TILES_X * TILES_Y;  // 256

// Exact replication of reference gather (rare fallback): clip flat index into
// padded (WP x WP) sdf, then pad value 1.0 or interior grid value.
__device__ __forceinline__ float fetch_pad(const float* __restrict__ gb, int idx) {
    idx = min(max(idx, 0), WP_ * WP_ - 1);
    int yy = idx / WP_;
    int xx = idx - yy * WP_;
    if (xx >= BND_ && xx < WP_ - BND_ && yy >= BND_ && yy < WP_ - BND_)
        return gb[(yy - BND_) * N_ + (xx - BND_)];
    return 1.0f;
}
} // namespace

__global__ __launch_bounds__(256) void advect_kernel(
    const float* __restrict__ grid,   // (B,N,N) fp32
    const float* __restrict__ vec,    // (B,N,N,2) fp32
    float* __restrict__ out)          // (B,N,N) fp32
{
    __shared__ float sg[CW_ * CH_];   // 31616 B

    int bid = blockIdx.x;
    int b   = bid / TILES_PER_IMG;
    int t   = bid - b * TILES_PER_IMG;
    int tyi = t / TILES_X;
    int txi = t - tyi * TILES_X;
    int it  = txi * TW_;              // tile origin (pixel coords)
    int jt  = tyi * TH_;

    int gi0 = it - 12;                // staged window origin (grid coords)
    int gj0 = jt - 9;

    const float* gb = grid + (size_t)b * NN_;
    int tid = threadIdx.x;

    // ---- Stage pad-extended grid window into LDS ----
    bool interior = (gi0 >= 0) && (gi0 + CW_ <= N_) && (gj0 >= 0) && (gj0 + CH_ <= N_);
    if (interior) {
        // pure float4 copy: 38 float4 per row x 52 rows = 1976
        constexpr int NV = (CW_ / 4) * CH_;   // 1976
        for (int e = tid; e < NV; e += 256) {
            int r  = e / (CW_ / 4);
            int c4 = e - r * (CW_ / 4);
            const float4* src = reinterpret_cast<const float4*>(gb + (gj0 + r) * N_ + gi0 + 4 * c4);
            *reinterpret_cast<float4*>(&sg[r * CW_ + 4 * c4]) = *src;
        }
    } else {
        for (int e = tid; e < CW_ * CH_; e += 256) {
            int r = e / CW_;
            int c = e - r * CW_;
            int gy = gj0 + r;
            int gx = gi0 + c;
            float v = 1.0f;
            if (gx >= 0 && gx < N_ && gy >= 0 && gy < N_)
                v = gb[gy * N_ + gx];
            sg[e] = v;
        }
    }
    __syncthreads();

    // ---- Compute 16 pixels per thread: 4-px quads over 4 rows ----
    int q  = tid & 31;                // quad-column index (pixel cols 4q..4q+3)
    int rg = tid >> 5;                // row group 0..7
    int i0 = it + 4 * q;

#pragma unroll
    for (int s = 0; s < 4; ++s) {
        int j = jt + rg + 8 * s;
        size_t pix = (size_t)b * NN_ + (size_t)j * N_ + i0;

        const float4* vp = reinterpret_cast<const float4*>(vec + pix * 2);
        float4 v01 = vp[0];           // vx0, vy0, vx1, vy1
        float4 v23 = vp[1];
        float vx[4] = {v01.x, v01.z, v23.x, v23.z};
        float vy[4] = {v01.y, v01.w, v23.y, v23.w};

        float res[4];
#pragma unroll
        for (int k = 0; k < 4; ++k) {
            // fp32 op order must match numpy: ((i+0.5) - vx) + 3.5
            float px = ((float)(i0 + k) + 0.5f - vx[k]) + 3.5f;
            float py = ((float)j        + 0.5f - vy[k]) + 3.5f;
            int x = (int)px;          // trunc toward zero == astype(int32)
            int y = (int)py;
            float fx = px - (float)x;
            float fy = py - (float)y;

            int lx = (x - BND_) - gi0;
            int ly = (y - BND_) - gj0;

            float g00, g01, g10, g11;
            if (lx >= 0 && lx <= CW_ - 2 && ly >= 0 && ly <= CH_ - 2) {
                const float* p = &sg[ly * CW_ + lx];
                g00 = p[0];
                g01 = p[1];
                g10 = p[CW_];
                g11 = p[CW_ + 1];
            } else {
                int idx = x + y * WP_;
                g00 = fetch_pad(gb, idx);
                g01 = fetch_pad(gb, idx + 1);
                g10 = fetch_pad(gb, idx + WP_);
                g11 = fetch_pad(gb, idx + WP_ + 1);
            }
            res[k] = g00 * (1.0f - fx) * (1.0f - fy)
                   + g01 * fx          * (1.0f - fy)
                   + g10 * (1.0f - fx) * fy
                   + g11 * fx          * fy;
        }

        float4 o = make_float4(res[0], res[1], res[2], res[3]);
        *reinterpret_cast<float4*>(out + pix) = o;
    }
}

extern "C" void kernel_launch(void* const* d_in, const int* in_sizes, int n_in,
                              void* d_out, int out_size, void* d_ws, size_t ws_size,
                              hipStream_t stream)
{
    const float* grid = (const float*)d_in[0];
    const float* vec  = (const float*)d_in[1];
    float* out = (float*)d_out;

    int total  = in_sizes[0];                     // B*N*N
    int nB     = total / NN_;                     // 16
    int blocks = nB * TILES_PER_IMG;              // 4096
    advect_kernel<<<blocks, 256, 0, stream>>>(grid, vec, out);
}

// Round 4
// 264.954 us; speedup vs baseline: 1.0861x; 1.0562x over previous
//
#include <hip/hip_runtime.h>

namespace {
constexpr int N_   = 1024;
constexpr int BND_ = 4;
constexpr int WP_  = N_ + 2 * BND_;   // 1032
constexpr int NN_  = N_ * N_;         // 1<<20

// Tile geometry: each 512-thread block computes a 128x32 pixel tile.
constexpr int TW_ = 128;
constexpr int TH_ = 32;
// Staged LDS window (grid coords [it-8, it+139] x [jt-8, jt+39]).
// Halo 8 covers |v| <= ~7 (max |N(0,1)| over 33M samples ~5.9); anything
// outside falls back to the exact global clip/pad path.
constexpr int CW_ = 148;              // 37 float4 per row, row stride %32 = 20
constexpr int CH_ = 48;
constexpr int HALO_ = 8;
constexpr int TILES_X = N_ / TW_;     // 8
constexpr int TILES_PER_IMG = TILES_X * (N_ / TH_);  // 256

// Exact replication of reference gather (rare fallback): clip flat index into
// padded (WP x WP) sdf, then pad value 1.0 or interior grid value.
__device__ __forceinline__ float fetch_pad(const float* __restrict__ gb, int idx) {
    idx = min(max(idx, 0), WP_ * WP_ - 1);
    int yy = idx / WP_;
    int xx = idx - yy * WP_;
    if (xx >= BND_ && xx < WP_ - BND_ && yy >= BND_ && yy < WP_ - BND_)
        return gb[(yy - BND_) * N_ + (xx - BND_)];
    return 1.0f;
}
} // namespace

__global__ __launch_bounds__(512) void advect_kernel(
    const float* __restrict__ grid,   // (B,N,N) fp32
    const float* __restrict__ vec,    // (B,N,N,2) fp32
    float* __restrict__ out)          // (B,N,N) fp32
{
    __shared__ float sg[CW_ * CH_];   // 28416 B

    int bid = blockIdx.x;
    int b   = bid >> 8;               // / TILES_PER_IMG (256)
    int t   = bid & 255;
    int tyi = t >> 3;                 // / TILES_X
    int txi = t & 7;
    int it  = txi * TW_;              // tile origin (pixel coords)
    int jt  = tyi * TH_;

    int gi0 = it - HALO_;             // staged window origin (grid coords), 16B-aligned
    int gj0 = jt - HALO_;

    const float* gb = grid + (size_t)b * NN_;
    int tid = threadIdx.x;
    int lx0 = tid & 31;               // lane x within 32-col group
    int rr  = tid >> 5;               // row 0..15

    // ---- Prefetch this thread's 8 displacement vectors BEFORE the barrier ----
    float2 pv[8];
#pragma unroll
    for (int s = 0; s < 2; ++s) {
        int j = jt + rr + 16 * s;
        const float2* vrow = reinterpret_cast<const float2*>(vec) + ((size_t)b * NN_ + (size_t)j * N_);
#pragma unroll
        for (int k = 0; k < 4; ++k) {
            int i = it + lx0 + 32 * k;
            pv[s * 4 + k] = vrow[i];
        }
    }

    // ---- Stage grid window into LDS ----
    bool interior = (gi0 >= 0) && (gi0 + CW_ <= N_) && (gj0 >= 0) && (gj0 + CH_ <= N_);
    if (interior) {
        constexpr int NV = (CW_ / 4) * CH_;   // 1776 float4
        for (int e = tid; e < NV; e += 512) {
            int r  = e / (CW_ / 4);
            int c4 = e - r * (CW_ / 4);
            const float4* src = reinterpret_cast<const float4*>(gb + (gj0 + r) * N_ + gi0 + 4 * c4);
            *reinterpret_cast<float4*>(&sg[r * CW_ + 4 * c4]) = *src;
        }
    } else {
        for (int e = tid; e < CW_ * CH_; e += 512) {
            int r = e / CW_;
            int c = e - r * CW_;
            int gy = gj0 + r;
            int gx = gi0 + c;
            float v = 1.0f;
            if (gx >= 0 && gx < N_ && gy >= 0 && gy < N_)
                v = gb[gy * N_ + gx];
            sg[e] = v;
        }
    }
    __syncthreads();

    // ---- Compute 8 pixels per thread: cols lx0+32k, rows rr+16s ----
#pragma unroll
    for (int s = 0; s < 2; ++s) {
        int j = jt + rr + 16 * s;
        size_t rowbase = (size_t)b * NN_ + (size_t)j * N_;
#pragma unroll
        for (int k = 0; k < 4; ++k) {
            int i = it + lx0 + 32 * k;
            float vx = pv[s * 4 + k].x;
            float vy = pv[s * 4 + k].y;
            // fp32 op order must match numpy: ((i+0.5) - vx) + 3.5
            float px = ((float)i + 0.5f - vx) + 3.5f;
            float py = ((float)j + 0.5f - vy) + 3.5f;
            int x = (int)px;          // trunc toward zero == astype(int32)
            int y = (int)py;
            float fx = px - (float)x;
            float fy = py - (float)y;

            int lx = (x - BND_) - gi0;
            int ly = (y - BND_) - gj0;

            float g00, g01, g10, g11;
            if (lx >= 0 && lx <= CW_ - 2 && ly >= 0 && ly <= CH_ - 2) {
                const float* p = &sg[ly * CW_ + lx];
                g00 = p[0];
                g01 = p[1];
                g10 = p[CW_];
                g11 = p[CW_ + 1];
            } else {
                int idx = x + y * WP_;
                g00 = fetch_pad(gb, idx);
                g01 = fetch_pad(gb, idx + 1);
                g10 = fetch_pad(gb, idx + WP_);
                g11 = fetch_pad(gb, idx + WP_ + 1);
            }
            out[rowbase + i] = g00 * (1.0f - fx) * (1.0f - fy)
                             + g01 * fx          * (1.0f - fy)
                             + g10 * (1.0f - fx) * fy
                             + g11 * fx          * fy;
        }
    }
}

extern "C" void kernel_launch(void* const* d_in, const int* in_sizes, int n_in,
                              void* d_out, int out_size, void* d_ws, size_t ws_size,
                              hipStream_t stream)
{
    const float* grid = (const float*)d_in[0];
    const float* vec  = (const float*)d_in[1];
    float* out = (float*)d_out;

    int total  = in_sizes[0];                     // B*N*N
    int nB     = total / NN_;                     // 16
    int blocks = nB * TILES_PER_IMG;              // 4096
    advect_kernel<<<blocks, 512, 0, stream>>>(grid, vec, out);
}